// Round 1
// baseline (1222.973 us; speedup 1.0000x reference)
//
#include <hip/hip_runtime.h>
#include <cstdint>

// ---------------------------------------------------------------------------
// FRNet IEU fused implementation for MI355X (gfx950), fp16 MFMA path.
//   B=8, C=256, H=W=128, WS=8 -> 131072 tokens, 2048 windows, 4 heads, hd=64
// Pipeline per branch (w then g):
//   GEMM  Xt(131072x256) @ Wqkv^T -> QKV (fp16)
//   GEMM  Xt @ fc1^T + b          -> Hbuf (fp16)
//   stats (per (b,ch) sum/sumsq)  -> InstanceNorm params
//   bitvec: gelu(norm(H)) . u  (u = fc2_w@bit_w folded)  -> x_bit
//   attention per window: S=QK^T, softmax, PV, * x_bit -> com (token-major)
// final: out = x*sigmoid(com_w) + com_g*(1-sigmoid(com_w))
// ---------------------------------------------------------------------------

typedef _Float16 half8 __attribute__((ext_vector_type(8)));
typedef float floatx4 __attribute__((ext_vector_type(4)));

__device__ __forceinline__ void async_cp16(const void* g, void* l) {
  __builtin_amdgcn_global_load_lds(
      (const __attribute__((address_space(1))) unsigned int*)g,
      (__attribute__((address_space(3))) unsigned int*)l, 16, 0, 0);
}

__device__ __forceinline__ unsigned pack2(_Float16 a, _Float16 b) {
  union { unsigned u; _Float16 h[2]; } t;
  t.h[0] = a; t.h[1] = b; return t.u;
}

// ---------------- weight prep: WT[br][n][k] fp16, n<768 = qkv^T, else fc1^T
__global__ void k_prep_w(const float* __restrict__ wqkv, const float* __restrict__ wfc1,
                         const float* __restrict__ gqkv, const float* __restrict__ gfc1,
                         _Float16* __restrict__ WT) {
  int id = blockIdx.x * 256 + threadIdx.x;          // < 655360
  int br = id / 327680;
  int rem = id - br * 327680;
  int n = rem >> 8, k = rem & 255;
  const float* qkv = br ? gqkv : wqkv;
  const float* fc1 = br ? gfc1 : wfc1;
  float v = (n < 768) ? qkv[k * 768 + n] : fc1[k * 512 + (n - 768)];
  WT[id] = (_Float16)v;
}

// ---------------- u = fc2_w @ bit_w (512), cbit = fc2_b.bit_w + bit_b
__global__ void k_prep_u(const float* __restrict__ wfc2, const float* __restrict__ wfc2b,
                         const float* __restrict__ wbit, const float* __restrict__ wbitb,
                         const float* __restrict__ gfc2, const float* __restrict__ gfc2b,
                         const float* __restrict__ gbit, const float* __restrict__ gbitb,
                         float* __restrict__ U, float* __restrict__ CB) {
  int br = blockIdx.x, i = threadIdx.x;
  const float* f2 = br ? gfc2 : wfc2;
  const float* bw = br ? gbit : wbit;
  float s = 0.f;
  for (int j = 0; j < 256; j++) s += f2[i * 256 + j] * bw[j];
  U[br * 512 + i] = s;
  if (i == 0) {
    const float* f2b = br ? gfc2b : wfc2b;
    const float* bb = br ? gbitb : wbitb;
    float c = bb[0];
    for (int j = 0; j < 256; j++) c += f2b[j] * bw[j];
    CB[br] = c;
  }
}

// ---------------- x (B,C,N) fp32 -> Xt (B*N, C) fp16 via LDS 64x64 tiles
__global__ __launch_bounds__(256) void k_transpose_x(const float* __restrict__ x,
                                                     _Float16* __restrict__ Xt) {
  __shared__ _Float16 t[64][66];
  const int b = blockIdx.z, c0 = blockIdx.y * 64;
  const size_t n0 = (size_t)blockIdx.x * 64;
  const int tid = threadIdx.x;
#pragma unroll
  for (int i = 0; i < 16; i++) {
    int idx = i * 256 + tid;
    int ci = idx >> 6, nj = idx & 63;
    t[ci][nj] = (_Float16)x[(((size_t)b * 256 + c0 + ci) << 14) + n0 + nj];
  }
  __syncthreads();
#pragma unroll
  for (int i = 0; i < 8; i++) {
    int idx = i * 256 + tid;
    int tok = idx >> 5, cp = idx & 31;
    unsigned u = pack2(t[cp * 2][tok], t[cp * 2 + 1][tok]);
    *(unsigned*)&Xt[((size_t)b * 16384 + n0 + tok) * 256 + c0 + cp * 2] = u;
  }
}

// ---------------- GEMM: C[m][n] = sum_k A[m][k]*Bt[n][k] (+bias), fp16 out.
// 128x128 tile, BK=32, global_load_lds w=16, XOR chunk swizzle (conflict-free
// ds_read_b128 fragments). 4 waves, each 64x64 (4x4 tiles of 16x16x32 MFMA).
__global__ __launch_bounds__(256) void k_gemm(const _Float16* __restrict__ A,
                                              const _Float16* __restrict__ Bt,
                                              const float* __restrict__ bias,
                                              _Float16* __restrict__ C, int ldc) {
  extern __shared__ _Float16 sm[];
  _Float16* As = sm;           // 4096 hw (8 KB)
  _Float16* Bs = sm + 4096;    // 4096 hw
  const int tid = threadIdx.x, wv = tid >> 6, lane = tid & 63;
  const int r15 = lane & 15, q = lane >> 4;
  const int wm = wv >> 1, wn = wv & 1;
  const size_t m0 = (size_t)blockIdx.y * 128;
  const int n0 = blockIdx.x * 128;
  const int srow = tid >> 2, sp = tid & 3;

  floatx4 acc[4][4] = {};

  for (int k0 = 0; k0 < 256; k0 += 32) {
#pragma unroll
    for (int j = 0; j < 2; j++) {
      const int row = j * 64 + srow;
      const int L = (sp - (row >> 1)) & 3;           // logical k-chunk at phys sp
      async_cp16(A + (m0 + row) * 256 + k0 + L * 8,
                 (char*)As + j * 4096 + wv * 1024);
      async_cp16(Bt + (size_t)(n0 + row) * 256 + k0 + L * 8,
                 (char*)sm + 8192 + j * 4096 + wv * 1024);
    }
    __syncthreads();
    half8 af[4], bf[4];
#pragma unroll
    for (int mi = 0; mi < 4; mi++) {
      const int row = wm * 64 + mi * 16 + r15;
      af[mi] = *(const half8*)&As[row * 32 + (((q + (row >> 1)) & 3) * 8)];
    }
#pragma unroll
    for (int ni = 0; ni < 4; ni++) {
      const int row = wn * 64 + ni * 16 + r15;
      bf[ni] = *(const half8*)&Bs[row * 32 + (((q + (row >> 1)) & 3) * 8)];
    }
#pragma unroll
    for (int mi = 0; mi < 4; mi++)
#pragma unroll
      for (int ni = 0; ni < 4; ni++)
        acc[mi][ni] = __builtin_amdgcn_mfma_f32_16x16x32_f16(af[mi], bf[ni], acc[mi][ni], 0, 0, 0);
    __syncthreads();
  }
  // epilogue: fp16 round-trip through LDS for coalesced 16B stores
  _Float16* Ct = sm;  // 128 x 136
#pragma unroll
  for (int mi = 0; mi < 4; mi++)
#pragma unroll
    for (int ni = 0; ni < 4; ni++)
#pragma unroll
      for (int rg = 0; rg < 4; rg++) {
        const int row = wm * 64 + mi * 16 + q * 4 + rg;
        const int col = wn * 64 + ni * 16 + r15;
        float v = acc[mi][ni][rg];
        if (bias) v += bias[n0 + col];
        Ct[row * 136 + col] = (_Float16)v;
      }
  __syncthreads();
#pragma unroll
  for (int i = 0; i < 8; i++) {
    const int cid = i * 256 + tid;
    const int row = cid >> 4, cc = cid & 15;
    *(half8*)&C[(m0 + row) * (size_t)ldc + n0 + cc * 8] = *(const half8*)&Ct[row * 136 + cc * 8];
  }
}

// ---------------- per (b,ch) sum/sumsq over H (fp16, ld=512)
__global__ __launch_bounds__(512) void k_stats(const _Float16* __restrict__ H,
                                               float* __restrict__ stats) {
  const int b = blockIdx.x >> 5, chunk = blockIdx.x & 31;
  const int sub = threadIdx.x & 63, rr = threadIdx.x >> 6;
  const size_t row0 = (size_t)b * 16384 + chunk * 512;
  float s[8] = {}, ss[8] = {};
  for (int t = 0; t < 64; t++) {
    const int r = rr + t * 8;
    const half8 v = *(const half8*)&H[(row0 + r) * 512 + sub * 8];
#pragma unroll
    for (int j = 0; j < 8; j++) { const float f = (float)v[j]; s[j] += f; ss[j] += f * f; }
  }
#pragma unroll
  for (int j = 0; j < 8; j++) {
    atomicAdd(&stats[b * 512 + sub * 8 + j], s[j]);
    atomicAdd(&stats[4096 + b * 512 + sub * 8 + j], ss[j]);
  }
}

// ---------------- x_bit[t] = relu(cbit + sum_ch gelu(norm(H)) * u[ch])
__global__ __launch_bounds__(256) void k_bitvec(const _Float16* __restrict__ H,
                                                const float* __restrict__ stats,
                                                const float* __restrict__ u,
                                                const float* __restrict__ cbp,
                                                float* __restrict__ xbit) {
  const int tid = threadIdx.x, wv = tid >> 6, lane = tid & 63;
  const int b = (int)(((size_t)blockIdx.x * 64) >> 14);
  const int c8 = lane * 8;
  float mu[8], rs[8], uu[8];
#pragma unroll
  for (int j = 0; j < 8; j++) {
    const float m = stats[b * 512 + c8 + j] * (1.f / 16384.f);
    const float vv = stats[4096 + b * 512 + c8 + j] * (1.f / 16384.f) - m * m;
    mu[j] = m; rs[j] = rsqrtf(vv + 1e-5f); uu[j] = u[c8 + j];
  }
  const float cbit = cbp[0];
  for (int i = 0; i < 16; i++) {
    const size_t row = (size_t)blockIdx.x * 64 + wv * 16 + i;
    const half8 hv = *(const half8*)&H[row * 512 + c8];
    float acc = 0.f;
#pragma unroll
    for (int j = 0; j < 8; j++) {
      const float hn = ((float)hv[j] - mu[j]) * rs[j];
      const float ge = 0.5f * hn * (1.f + erff(hn * 0.70710678118654752f));
      acc += ge * uu[j];
    }
    for (int off = 32; off; off >>= 1) acc += __shfl_down(acc, off);
    if (lane == 0) xbit[row] = fmaxf(acc + cbit, 0.f);
  }
}

// ---------------- windowed attention, 1 block = 1 window (512 thr, 8 waves),
// 2 heads per phase (LDS exactly 64 KB). Writes com token-major [b*N+n][256].
#define AT_VT 16384
#define AT_P  24576
__global__ __launch_bounds__(512) void k_attn(const _Float16* __restrict__ QKV,
                                              const float* __restrict__ xbit,
                                              _Float16* __restrict__ com) {
  extern __shared__ _Float16 sm[];
  const int tid = threadIdx.x, wv = tid >> 6, lane = tid & 63;
  const int r15 = lane & 15, q = lane >> 4;
  const int bid = blockIdx.x;
  const int b = bid >> 8, wx = (bid >> 4) & 15, wy = bid & 15;
  const size_t rowbase = (size_t)b << 14;
  const int hl = wv >> 2, mq = wv & 3;

  for (int hp = 0; hp < 2; hp++) {
    // stage Q,K (2 heads): qk[64 tok][256 hw], XOR-swizzled chunks
#pragma unroll
    for (int call = 0; call < 4; call++) {
      const int c = call * 512 + tid;
      const int tok = c >> 5, p = c & 31;
      const int L = (p & 24) | ((p & 7) ^ (tok & 7));
      const int col = (L < 16) ? (hp * 128 + L * 8) : (256 + hp * 128 + (L - 16) * 8);
      const int n = ((wx * 8 + (tok >> 3)) * 128) + wy * 8 + (tok & 7);
      async_cp16(QKV + (rowbase + n) * 768 + col, (char*)sm + call * 8192 + wv * 1024);
    }
    // stage V transposed: vt[head][d][tok], swizzled
#pragma unroll
    for (int i = 0; i < 2; i++) {
      const int c = i * 512 + tid;
      const int tok = c >> 4, dch = c & 15;
      const int n = ((wx * 8 + (tok >> 3)) * 128) + wy * 8 + (tok & 7);
      half8 v = *(const half8*)(QKV + (rowbase + n) * 768 + 512 + hp * 128 + dch * 8);
#pragma unroll
      for (int jj = 0; jj < 8; jj++) {
        const int dl = dch * 8 + jj;
        const int h2 = dl >> 6, dd = dl & 63;
        const int pc = (tok >> 3) ^ (dd & 7);
        sm[AT_VT + h2 * 4096 + dd * 64 + pc * 8 + (tok & 7)] = v[jj];
      }
    }
    __syncthreads();

    // S = Q K^T  (wave = head hl, row quarter mq: rows mq*16..+16)
    floatx4 s[4] = {};
#pragma unroll
    for (int kk = 0; kk < 2; kk++) {
      const int atok = mq * 16 + r15;
      const int pq = (hl * 8) | ((kk * 4 + q) ^ (atok & 7));
      const half8 af = *(const half8*)&sm[atok * 256 + pq * 8];
#pragma unroll
      for (int ni = 0; ni < 4; ni++) {
        const int ktok = ni * 16 + r15;
        const int pk = (16 + hl * 8) | ((kk * 4 + q) ^ (ktok & 7));
        const half8 bf = *(const half8*)&sm[ktok * 256 + pk * 8];
        s[ni] = __builtin_amdgcn_mfma_f32_16x16x32_f16(af, bf, s[ni], 0, 0, 0);
      }
    }
#pragma unroll
    for (int ni = 0; ni < 4; ni++) s[ni] *= 0.125f;   // hd^-0.5

    // softmax per row (fp32), write P fp16 swizzled
#pragma unroll
    for (int rg = 0; rg < 4; rg++) {
      float m = fmaxf(fmaxf(s[0][rg], s[1][rg]), fmaxf(s[2][rg], s[3][rg]));
      for (int msk = 1; msk < 16; msk <<= 1) m = fmaxf(m, __shfl_xor(m, msk));
      float e[4];
      float sum = 0.f;
#pragma unroll
      for (int ni = 0; ni < 4; ni++) { e[ni] = expf(s[ni][rg] - m); sum += e[ni]; }
      for (int msk = 1; msk < 16; msk <<= 1) sum += __shfl_xor(sum, msk);
      const float inv = 1.f / sum;
      const int row = mq * 16 + q * 4 + rg;
      const int base = AT_P + hl * 4096 + row * 64;
      const int rx = row & 7;
#pragma unroll
      for (int ni = 0; ni < 4; ni++) {
        const int col = ni * 16 + r15;
        sm[base + (((col >> 3) ^ rx) * 8) + (col & 7)] = (_Float16)(e[ni] * inv);
      }
    }

    // ctx = P V
    floatx4 o[4] = {};
#pragma unroll
    for (int kk = 0; kk < 2; kk++) {
      const int arow = mq * 16 + r15;
      const int pcp = (kk * 4 + q) ^ (arow & 7);
      const half8 pf = *(const half8*)&sm[AT_P + hl * 4096 + arow * 64 + pcp * 8];
#pragma unroll
      for (int ni = 0; ni < 4; ni++) {
        const int dd = ni * 16 + r15;
        const int pcv = (kk * 4 + q) ^ (dd & 7);
        const half8 vf = *(const half8*)&sm[AT_VT + hl * 4096 + dd * 64 + pcv * 8];
        o[ni] = __builtin_amdgcn_mfma_f32_16x16x32_f16(pf, vf, o[ni], 0, 0, 0);
      }
    }
    __syncthreads();
    // ctx -> sm[0..8192) as [tok][128]
#pragma unroll
    for (int ni = 0; ni < 4; ni++)
#pragma unroll
      for (int rg = 0; rg < 4; rg++) {
        const int row = mq * 16 + q * 4 + rg;
        sm[row * 128 + hl * 64 + ni * 16 + r15] = (_Float16)o[ni][rg];
      }
    __syncthreads();
    // write com rows (scaled by x_bit), coalesced 256 B per token row
#pragma unroll
    for (int i = 0; i < 2; i++) {
      const int c = i * 512 + tid;
      const int tok = c >> 4, cc = c & 15;
      const int n = ((wx * 8 + (tok >> 3)) * 128) + wy * 8 + (tok & 7);
      const float xb = xbit[(rowbase) + n];
      const half8 v = *(const half8*)&sm[tok * 128 + cc * 8];
      half8 ov;
#pragma unroll
      for (int jj = 0; jj < 8; jj++) ov[jj] = (_Float16)((float)v[jj] * xb);
      *(half8*)&com[(rowbase + n) * 256 + hp * 128 + cc * 8] = ov;
    }
    __syncthreads();
  }
}

// ---------------- out = x*sigmoid(com_w) + com_g*(1-sigmoid(com_w))
__global__ __launch_bounds__(256) void k_final(const float* __restrict__ x,
                                               const _Float16* __restrict__ comw,
                                               const _Float16* __restrict__ comg,
                                               float* __restrict__ out) {
  __shared__ _Float16 tw[64][66], tg[64][66];
  const int b = blockIdx.z, c0 = blockIdx.y * 64;
  const size_t n0 = (size_t)blockIdx.x * 64;
  const int tid = threadIdx.x;
#pragma unroll
  for (int i = 0; i < 8; i++) {
    int idx = i * 256 + tid;
    int n = idx >> 5, cp = idx & 31;
    size_t gi = ((size_t)b * 16384 + n0 + n) * 256 + c0 + cp * 2;
    *(unsigned*)&tw[n][cp * 2] = *(const unsigned*)&comw[gi];
    *(unsigned*)&tg[n][cp * 2] = *(const unsigned*)&comg[gi];
  }
  __syncthreads();
  const int n = tid & 63, cq = tid >> 6;
#pragma unroll
  for (int i = 0; i < 16; i++) {
    const int c = cq * 16 + i;
    const float vw = (float)tw[n][c];
    const float vg = (float)tg[n][c];
    const float sg = 1.f / (1.f + expf(-vw));
    const size_t gi = (((size_t)b * 256 + c0 + c) << 14) + n0 + n;
    out[gi] = x[gi] * sg + vg * (1.f - sg);
  }
}

// ---------------------------------------------------------------------------
extern "C" void kernel_launch(void* const* d_in, const int* in_sizes, int n_in,
                              void* d_out, int out_size, void* d_ws, size_t ws_size,
                              hipStream_t stream) {
  (void)in_sizes; (void)n_in; (void)out_size; (void)ws_size;
  const float* x = (const float*)d_in[0];
  // g: 1..7, w: 8..14 (qkv, fc1w, fc1b, fc2w, fc2b, bitw, bitb)
  char* ws = (char*)d_ws;
  size_t off = 0;
  auto take = [&](size_t bytes) { char* p = ws + off; off = (off + bytes + 255) & ~(size_t)255; return p; };
  _Float16* WT   = (_Float16*)take(2ull * 1280 * 256 * 2);
  float*    UVEC = (float*)take(2ull * 512 * 4);
  float*    CBIT = (float*)take(2ull * 4);
  float*    STATS= (float*)take(2ull * 8192 * 4);
  float*    XBIT = (float*)take(131072ull * 4);
  _Float16* XT   = (_Float16*)take(131072ull * 256 * 2);
  _Float16* QKV  = (_Float16*)take(131072ull * 768 * 2);
  _Float16* Hbuf = (_Float16*)take(131072ull * 512 * 2);
  _Float16* COMW = (_Float16*)take(131072ull * 256 * 2);
  _Float16* COMG = Hbuf;  // alias: H dead before g-branch attention writes

  hipMemsetAsync(STATS, 0, 2ull * 8192 * 4, stream);
  k_prep_w<<<2560, 256, 0, stream>>>((const float*)d_in[8], (const float*)d_in[9],
                                     (const float*)d_in[1], (const float*)d_in[2], WT);
  k_prep_u<<<2, 512, 0, stream>>>((const float*)d_in[11], (const float*)d_in[12],
                                  (const float*)d_in[13], (const float*)d_in[14],
                                  (const float*)d_in[4], (const float*)d_in[5],
                                  (const float*)d_in[6], (const float*)d_in[7],
                                  UVEC, CBIT);
  k_transpose_x<<<dim3(256, 4, 8), 256, 0, stream>>>(x, XT);

  for (int br = 0; br < 2; br++) {  // br 0 = w (sigmoid gate), br 1 = g (com)
    const _Float16* WTb = WT + (size_t)br * 1280 * 256;
    const float* fc1b = (const float*)d_in[br == 0 ? 10 : 3];
    k_gemm<<<dim3(6, 1024), 256, 34816, stream>>>(XT, WTb, nullptr, QKV, 768);
    k_gemm<<<dim3(4, 1024), 256, 34816, stream>>>(XT, WTb + 768 * 256, fc1b, Hbuf, 512);
    k_stats<<<256, 512, 0, stream>>>(Hbuf, STATS + br * 8192);
    k_bitvec<<<2048, 256, 0, stream>>>(Hbuf, STATS + br * 8192, UVEC + br * 512,
                                       CBIT + br, XBIT);
    k_attn<<<2048, 512, 65536, stream>>>(QKV, XBIT, br == 0 ? COMW : COMG);
  }
  k_final<<<dim3(256, 4, 8), 256, 0, stream>>>(x, COMW, COMG, (float*)d_out);
}

// Round 2
// 980.242 us; speedup vs baseline: 1.2476x; 1.2476x over previous
//
#include <hip/hip_runtime.h>
#include <cstdint>

// ---------------------------------------------------------------------------
// FRNet IEU fused implementation for MI355X (gfx950), fp16 MFMA path.
//   B=8, C=256, H=W=128, WS=8 -> 131072 tokens, 2048 windows, 4 heads, hd=64
// Pipeline per branch (w then g):
//   GEMM  Xt(131072x256) @ Wqkv^T -> QKV (fp16)
//   GEMM  Xt @ fc1^T + b          -> Hbuf (fp16)  [+ fused per-(b,ch) stats]
//   bitvec: gelu(norm(H)) . u  (u = fc2_w@bit_w folded)  -> x_bit
//   attention per window: S=QK^T, softmax, PV, * x_bit -> com (token-major)
// final: out = x*sigmoid(com_w) + com_g*(1-sigmoid(com_w))
// R2: k_stats (116us x2, 14% HBM, latency-bound) folded into GEMM epilogue.
// ---------------------------------------------------------------------------

typedef _Float16 half8 __attribute__((ext_vector_type(8)));
typedef float floatx4 __attribute__((ext_vector_type(4)));

__device__ __forceinline__ void async_cp16(const void* g, void* l) {
  __builtin_amdgcn_global_load_lds(
      (const __attribute__((address_space(1))) unsigned int*)g,
      (__attribute__((address_space(3))) unsigned int*)l, 16, 0, 0);
}

__device__ __forceinline__ unsigned pack2(_Float16 a, _Float16 b) {
  union { unsigned u; _Float16 h[2]; } t;
  t.h[0] = a; t.h[1] = b; return t.u;
}

// ---------------- weight prep: WT[br][n][k] fp16, n<768 = qkv^T, else fc1^T
__global__ void k_prep_w(const float* __restrict__ wqkv, const float* __restrict__ wfc1,
                         const float* __restrict__ gqkv, const float* __restrict__ gfc1,
                         _Float16* __restrict__ WT) {
  int id = blockIdx.x * 256 + threadIdx.x;          // < 655360
  int br = id / 327680;
  int rem = id - br * 327680;
  int n = rem >> 8, k = rem & 255;
  const float* qkv = br ? gqkv : wqkv;
  const float* fc1 = br ? gfc1 : wfc1;
  float v = (n < 768) ? qkv[k * 768 + n] : fc1[k * 512 + (n - 768)];
  WT[id] = (_Float16)v;
}

// ---------------- u = fc2_w @ bit_w (512), cbit = fc2_b.bit_w + bit_b
__global__ void k_prep_u(const float* __restrict__ wfc2, const float* __restrict__ wfc2b,
                         const float* __restrict__ wbit, const float* __restrict__ wbitb,
                         const float* __restrict__ gfc2, const float* __restrict__ gfc2b,
                         const float* __restrict__ gbit, const float* __restrict__ gbitb,
                         float* __restrict__ U, float* __restrict__ CB) {
  int br = blockIdx.x, i = threadIdx.x;
  const float* f2 = br ? gfc2 : wfc2;
  const float* bw = br ? gbit : wbit;
  float s = 0.f;
  for (int j = 0; j < 256; j++) s += f2[i * 256 + j] * bw[j];
  U[br * 512 + i] = s;
  if (i == 0) {
    const float* f2b = br ? gfc2b : wfc2b;
    const float* bb = br ? gbitb : wbitb;
    float c = bb[0];
    for (int j = 0; j < 256; j++) c += f2b[j] * bw[j];
    CB[br] = c;
  }
}

// ---------------- x (B,C,N) fp32 -> Xt (B*N, C) fp16 via LDS 64x64 tiles
__global__ __launch_bounds__(256) void k_transpose_x(const float* __restrict__ x,
                                                     _Float16* __restrict__ Xt) {
  __shared__ _Float16 t[64][66];
  const int b = blockIdx.z, c0 = blockIdx.y * 64;
  const size_t n0 = (size_t)blockIdx.x * 64;
  const int tid = threadIdx.x;
#pragma unroll
  for (int i = 0; i < 16; i++) {
    int idx = i * 256 + tid;
    int ci = idx >> 6, nj = idx & 63;
    t[ci][nj] = (_Float16)x[(((size_t)b * 256 + c0 + ci) << 14) + n0 + nj];
  }
  __syncthreads();
#pragma unroll
  for (int i = 0; i < 8; i++) {
    int idx = i * 256 + tid;
    int tok = idx >> 5, cp = idx & 31;
    unsigned u = pack2(t[cp * 2][tok], t[cp * 2 + 1][tok]);
    *(unsigned*)&Xt[((size_t)b * 16384 + n0 + tok) * 256 + c0 + cp * 2] = u;
  }
}

// ---------------- GEMM: C[m][n] = sum_k A[m][k]*Bt[n][k] (+bias), fp16 out.
// 128x128 tile, BK=32, global_load_lds w=16, XOR chunk swizzle (conflict-free
// ds_read_b128 fragments). 4 waves, each 64x64 (4x4 tiles of 16x16x32 MFMA).
// If stats != null: fused per-(b,col) sum/sumsq reduction (InstanceNorm).
__global__ __launch_bounds__(256) void k_gemm(const _Float16* __restrict__ A,
                                              const _Float16* __restrict__ Bt,
                                              const float* __restrict__ bias,
                                              _Float16* __restrict__ C, int ldc,
                                              float* __restrict__ stats) {
  extern __shared__ _Float16 sm[];
  _Float16* As = sm;           // 4096 hw (8 KB)
  _Float16* Bs = sm + 4096;    // 4096 hw
  const int tid = threadIdx.x, wv = tid >> 6, lane = tid & 63;
  const int r15 = lane & 15, q = lane >> 4;
  const int wm = wv >> 1, wn = wv & 1;
  const size_t m0 = (size_t)blockIdx.y * 128;
  const int n0 = blockIdx.x * 128;
  const int srow = tid >> 2, sp = tid & 3;

  floatx4 acc[4][4] = {};

  for (int k0 = 0; k0 < 256; k0 += 32) {
#pragma unroll
    for (int j = 0; j < 2; j++) {
      const int row = j * 64 + srow;
      const int L = (sp - (row >> 1)) & 3;           // logical k-chunk at phys sp
      async_cp16(A + (m0 + row) * 256 + k0 + L * 8,
                 (char*)As + j * 4096 + wv * 1024);
      async_cp16(Bt + (size_t)(n0 + row) * 256 + k0 + L * 8,
                 (char*)sm + 8192 + j * 4096 + wv * 1024);
    }
    __syncthreads();
    half8 af[4], bf[4];
#pragma unroll
    for (int mi = 0; mi < 4; mi++) {
      const int row = wm * 64 + mi * 16 + r15;
      af[mi] = *(const half8*)&As[row * 32 + (((q + (row >> 1)) & 3) * 8)];
    }
#pragma unroll
    for (int ni = 0; ni < 4; ni++) {
      const int row = wn * 64 + ni * 16 + r15;
      bf[ni] = *(const half8*)&Bs[row * 32 + (((q + (row >> 1)) & 3) * 8)];
    }
#pragma unroll
    for (int mi = 0; mi < 4; mi++)
#pragma unroll
      for (int ni = 0; ni < 4; ni++)
        acc[mi][ni] = __builtin_amdgcn_mfma_f32_16x16x32_f16(af[mi], bf[ni], acc[mi][ni], 0, 0, 0);
    __syncthreads();
  }
  // epilogue: fp16 round-trip through LDS for coalesced 16B stores; fused
  // column sum/sumsq (col = wn*64+ni*16+r15 is q-independent -> shfl_xor
  // 16/32 reduces 64 rows in-register; cross-wm combine via LDS scratch;
  // one atomicAdd per column per block).
  _Float16* Ct = sm;                      // 128 x 136 fp16
  float* scr = (float*)(sm + 128 * 136);  // 256 fp32 (sum[128], sq[128])
  float ps[4], pq[4];
#pragma unroll
  for (int ni = 0; ni < 4; ni++) {
    const int col = wn * 64 + ni * 16 + r15;
    const float bv = bias ? bias[n0 + col] : 0.f;
    float s = 0.f, q2 = 0.f;
#pragma unroll
    for (int mi = 0; mi < 4; mi++)
#pragma unroll
      for (int rg = 0; rg < 4; rg++) {
        const int row = wm * 64 + mi * 16 + q * 4 + rg;
        const float v = acc[mi][ni][rg] + bv;
        Ct[row * 136 + col] = (_Float16)v;
        s += v; q2 += v * v;
      }
    ps[ni] = s; pq[ni] = q2;
  }
  if (stats) {
#pragma unroll
    for (int ni = 0; ni < 4; ni++) {
      for (int msk = 16; msk < 64; msk <<= 1) {
        ps[ni] += __shfl_xor(ps[ni], msk);
        pq[ni] += __shfl_xor(pq[ni], msk);
      }
    }
    if (q == 0 && wm == 1) {
#pragma unroll
      for (int ni = 0; ni < 4; ni++) {
        const int col = wn * 64 + ni * 16 + r15;
        scr[col] = ps[ni];
        scr[128 + col] = pq[ni];
      }
    }
  }
  __syncthreads();
  if (stats && q == 0 && wm == 0) {
    const int b = (int)(m0 >> 14);
#pragma unroll
    for (int ni = 0; ni < 4; ni++) {
      const int col = wn * 64 + ni * 16 + r15;
      atomicAdd(&stats[b * 512 + n0 + col], ps[ni] + scr[col]);
      atomicAdd(&stats[4096 + b * 512 + n0 + col], pq[ni] + scr[128 + col]);
    }
  }
#pragma unroll
  for (int i = 0; i < 8; i++) {
    const int cid = i * 256 + tid;
    const int row = cid >> 4, cc = cid & 15;
    *(half8*)&C[(m0 + row) * (size_t)ldc + n0 + cc * 8] = *(const half8*)&Ct[row * 136 + cc * 8];
  }
}

// ---------------- x_bit[t] = relu(cbit + sum_ch gelu(norm(H)) * u[ch])
__global__ __launch_bounds__(256) void k_bitvec(const _Float16* __restrict__ H,
                                                const float* __restrict__ stats,
                                                const float* __restrict__ u,
                                                const float* __restrict__ cbp,
                                                float* __restrict__ xbit) {
  const int tid = threadIdx.x, wv = tid >> 6, lane = tid & 63;
  const int b = (int)(((size_t)blockIdx.x * 64) >> 14);
  const int c8 = lane * 8;
  float mu[8], rs[8], uu[8];
#pragma unroll
  for (int j = 0; j < 8; j++) {
    const float m = stats[b * 512 + c8 + j] * (1.f / 16384.f);
    const float vv = stats[4096 + b * 512 + c8 + j] * (1.f / 16384.f) - m * m;
    mu[j] = m; rs[j] = rsqrtf(vv + 1e-5f); uu[j] = u[c8 + j];
  }
  const float cbit = cbp[0];
  for (int i = 0; i < 16; i++) {
    const size_t row = (size_t)blockIdx.x * 64 + wv * 16 + i;
    const half8 hv = *(const half8*)&H[row * 512 + c8];
    float acc = 0.f;
#pragma unroll
    for (int j = 0; j < 8; j++) {
      const float hn = ((float)hv[j] - mu[j]) * rs[j];
      const float ge = 0.5f * hn * (1.f + erff(hn * 0.70710678118654752f));
      acc += ge * uu[j];
    }
    for (int off = 32; off; off >>= 1) acc += __shfl_down(acc, off);
    if (lane == 0) xbit[row] = fmaxf(acc + cbit, 0.f);
  }
}

// ---------------- windowed attention, 1 block = 1 window (512 thr, 8 waves),
// 2 heads per phase (LDS exactly 64 KB). Writes com token-major [b*N+n][256].
#define AT_VT 16384
#define AT_P  24576
__global__ __launch_bounds__(512) void k_attn(const _Float16* __restrict__ QKV,
                                              const float* __restrict__ xbit,
                                              _Float16* __restrict__ com) {
  extern __shared__ _Float16 sm[];
  const int tid = threadIdx.x, wv = tid >> 6, lane = tid & 63;
  const int r15 = lane & 15, q = lane >> 4;
  const int bid = blockIdx.x;
  const int b = bid >> 8, wx = (bid >> 4) & 15, wy = bid & 15;
  const size_t rowbase = (size_t)b << 14;
  const int hl = wv >> 2, mq = wv & 3;

  for (int hp = 0; hp < 2; hp++) {
    // stage Q,K (2 heads): qk[64 tok][256 hw], XOR-swizzled chunks
#pragma unroll
    for (int call = 0; call < 4; call++) {
      const int c = call * 512 + tid;
      const int tok = c >> 5, p = c & 31;
      const int L = (p & 24) | ((p & 7) ^ (tok & 7));
      const int col = (L < 16) ? (hp * 128 + L * 8) : (256 + hp * 128 + (L - 16) * 8);
      const int n = ((wx * 8 + (tok >> 3)) * 128) + wy * 8 + (tok & 7);
      async_cp16(QKV + (rowbase + n) * 768 + col, (char*)sm + call * 8192 + wv * 1024);
    }
    // stage V transposed: vt[head][d][tok], swizzled
#pragma unroll
    for (int i = 0; i < 2; i++) {
      const int c = i * 512 + tid;
      const int tok = c >> 4, dch = c & 15;
      const int n = ((wx * 8 + (tok >> 3)) * 128) + wy * 8 + (tok & 7);
      half8 v = *(const half8*)(QKV + (rowbase + n) * 768 + 512 + hp * 128 + dch * 8);
#pragma unroll
      for (int jj = 0; jj < 8; jj++) {
        const int dl = dch * 8 + jj;
        const int h2 = dl >> 6, dd = dl & 63;
        const int pc = (tok >> 3) ^ (dd & 7);
        sm[AT_VT + h2 * 4096 + dd * 64 + pc * 8 + (tok & 7)] = v[jj];
      }
    }
    __syncthreads();

    // S = Q K^T  (wave = head hl, row quarter mq: rows mq*16..+16)
    floatx4 s[4] = {};
#pragma unroll
    for (int kk = 0; kk < 2; kk++) {
      const int atok = mq * 16 + r15;
      const int pq = (hl * 8) | ((kk * 4 + q) ^ (atok & 7));
      const half8 af = *(const half8*)&sm[atok * 256 + pq * 8];
#pragma unroll
      for (int ni = 0; ni < 4; ni++) {
        const int ktok = ni * 16 + r15;
        const int pk = (16 + hl * 8) | ((kk * 4 + q) ^ (ktok & 7));
        const half8 bf = *(const half8*)&sm[ktok * 256 + pk * 8];
        s[ni] = __builtin_amdgcn_mfma_f32_16x16x32_f16(af, bf, s[ni], 0, 0, 0);
      }
    }
#pragma unroll
    for (int ni = 0; ni < 4; ni++) s[ni] *= 0.125f;   // hd^-0.5

    // softmax per row (fp32), write P fp16 swizzled
#pragma unroll
    for (int rg = 0; rg < 4; rg++) {
      float m = fmaxf(fmaxf(s[0][rg], s[1][rg]), fmaxf(s[2][rg], s[3][rg]));
      for (int msk = 1; msk < 16; msk <<= 1) m = fmaxf(m, __shfl_xor(m, msk));
      float e[4];
      float sum = 0.f;
#pragma unroll
      for (int ni = 0; ni < 4; ni++) { e[ni] = expf(s[ni][rg] - m); sum += e[ni]; }
      for (int msk = 1; msk < 16; msk <<= 1) sum += __shfl_xor(sum, msk);
      const float inv = 1.f / sum;
      const int row = mq * 16 + q * 4 + rg;
      const int base = AT_P + hl * 4096 + row * 64;
      const int rx = row & 7;
#pragma unroll
      for (int ni = 0; ni < 4; ni++) {
        const int col = ni * 16 + r15;
        sm[base + (((col >> 3) ^ rx) * 8) + (col & 7)] = (_Float16)(e[ni] * inv);
      }
    }

    // ctx = P V
    floatx4 o[4] = {};
#pragma unroll
    for (int kk = 0; kk < 2; kk++) {
      const int arow = mq * 16 + r15;
      const int pcp = (kk * 4 + q) ^ (arow & 7);
      const half8 pf = *(const half8*)&sm[AT_P + hl * 4096 + arow * 64 + pcp * 8];
#pragma unroll
      for (int ni = 0; ni < 4; ni++) {
        const int dd = ni * 16 + r15;
        const int pcv = (kk * 4 + q) ^ (dd & 7);
        const half8 vf = *(const half8*)&sm[AT_VT + hl * 4096 + dd * 64 + pcv * 8];
        o[ni] = __builtin_amdgcn_mfma_f32_16x16x32_f16(pf, vf, o[ni], 0, 0, 0);
      }
    }
    __syncthreads();
    // ctx -> sm[0..8192) as [tok][128]
#pragma unroll
    for (int ni = 0; ni < 4; ni++)
#pragma unroll
      for (int rg = 0; rg < 4; rg++) {
        const int row = mq * 16 + q * 4 + rg;
        sm[row * 128 + hl * 64 + ni * 16 + r15] = (_Float16)o[ni][rg];
      }
    __syncthreads();
    // write com rows (scaled by x_bit), coalesced 256 B per token row
#pragma unroll
    for (int i = 0; i < 2; i++) {
      const int c = i * 512 + tid;
      const int tok = c >> 4, cc = c & 15;
      const int n = ((wx * 8 + (tok >> 3)) * 128) + wy * 8 + (tok & 7);
      const float xb = xbit[(rowbase) + n];
      const half8 v = *(const half8*)&sm[tok * 128 + cc * 8];
      half8 ov;
#pragma unroll
      for (int jj = 0; jj < 8; jj++) ov[jj] = (_Float16)((float)v[jj] * xb);
      *(half8*)&com[(rowbase + n) * 256 + hp * 128 + cc * 8] = ov;
    }
    __syncthreads();
  }
}

// ---------------- out = x*sigmoid(com_w) + com_g*(1-sigmoid(com_w))
__global__ __launch_bounds__(256) void k_final(const float* __restrict__ x,
                                               const _Float16* __restrict__ comw,
                                               const _Float16* __restrict__ comg,
                                               float* __restrict__ out) {
  __shared__ _Float16 tw[64][66], tg[64][66];
  const int b = blockIdx.z, c0 = blockIdx.y * 64;
  const size_t n0 = (size_t)blockIdx.x * 64;
  const int tid = threadIdx.x;
#pragma unroll
  for (int i = 0; i < 8; i++) {
    int idx = i * 256 + tid;
    int n = idx >> 5, cp = idx & 31;
    size_t gi = ((size_t)b * 16384 + n0 + n) * 256 + c0 + cp * 2;
    *(unsigned*)&tw[n][cp * 2] = *(const unsigned*)&comw[gi];
    *(unsigned*)&tg[n][cp * 2] = *(const unsigned*)&comg[gi];
  }
  __syncthreads();
  const int n = tid & 63, cq = tid >> 6;
#pragma unroll
  for (int i = 0; i < 16; i++) {
    const int c = cq * 16 + i;
    const float vw = (float)tw[n][c];
    const float vg = (float)tg[n][c];
    const float sg = 1.f / (1.f + expf(-vw));
    const size_t gi = (((size_t)b * 256 + c0 + c) << 14) + n0 + n;
    out[gi] = x[gi] * sg + vg * (1.f - sg);
  }
}

// ---------------------------------------------------------------------------
extern "C" void kernel_launch(void* const* d_in, const int* in_sizes, int n_in,
                              void* d_out, int out_size, void* d_ws, size_t ws_size,
                              hipStream_t stream) {
  (void)in_sizes; (void)n_in; (void)out_size; (void)ws_size;
  const float* x = (const float*)d_in[0];
  // g: 1..7, w: 8..14 (qkv, fc1w, fc1b, fc2w, fc2b, bitw, bitb)
  char* ws = (char*)d_ws;
  size_t off = 0;
  auto take = [&](size_t bytes) { char* p = ws + off; off = (off + bytes + 255) & ~(size_t)255; return p; };
  _Float16* WT   = (_Float16*)take(2ull * 1280 * 256 * 2);
  float*    UVEC = (float*)take(2ull * 512 * 4);
  float*    CBIT = (float*)take(2ull * 4);
  float*    STATS= (float*)take(2ull * 8192 * 4);
  float*    XBIT = (float*)take(131072ull * 4);
  _Float16* XT   = (_Float16*)take(131072ull * 256 * 2);
  _Float16* QKV  = (_Float16*)take(131072ull * 768 * 2);
  _Float16* Hbuf = (_Float16*)take(131072ull * 512 * 2);
  _Float16* COMW = (_Float16*)take(131072ull * 256 * 2);
  _Float16* COMG = Hbuf;  // alias: H dead before g-branch attention writes

  hipMemsetAsync(STATS, 0, 2ull * 8192 * 4, stream);
  k_prep_w<<<2560, 256, 0, stream>>>((const float*)d_in[8], (const float*)d_in[9],
                                     (const float*)d_in[1], (const float*)d_in[2], WT);
  k_prep_u<<<2, 512, 0, stream>>>((const float*)d_in[11], (const float*)d_in[12],
                                  (const float*)d_in[13], (const float*)d_in[14],
                                  (const float*)d_in[4], (const float*)d_in[5],
                                  (const float*)d_in[6], (const float*)d_in[7],
                                  UVEC, CBIT);
  k_transpose_x<<<dim3(256, 4, 8), 256, 0, stream>>>(x, XT);

  for (int br = 0; br < 2; br++) {  // br 0 = w (sigmoid gate), br 1 = g (com)
    const _Float16* WTb = WT + (size_t)br * 1280 * 256;
    const float* fc1b = (const float*)d_in[br == 0 ? 10 : 3];
    k_gemm<<<dim3(6, 1024), 256, 35840, stream>>>(XT, WTb, nullptr, QKV, 768, nullptr);
    k_gemm<<<dim3(4, 1024), 256, 35840, stream>>>(XT, WTb + 768 * 256, fc1b, Hbuf, 512,
                                                  (float*)STATS + br * 8192);
    k_bitvec<<<2048, 256, 0, stream>>>(Hbuf, STATS + br * 8192, UVEC + br * 512,
                                       CBIT + br, XBIT);
    k_attn<<<2048, 512, 65536, stream>>>(QKV, XBIT, br == 0 ? COMW : COMG);
  }
  k_final<<<dim3(256, 4, 8), 256, 0, stream>>>(x, COMW, COMG, (float*)d_out);
}